// Round 1
// baseline (164.537 us; speedup 1.0000x reference)
//
#include <hip/hip_runtime.h>

typedef unsigned short u16;
typedef __attribute__((ext_vector_type(8))) short short8;
typedef __attribute__((ext_vector_type(4))) float f32x4;
typedef __attribute__((ext_vector_type(4))) u16 u16x4;

#define GPTR(p) ((const __attribute__((address_space(1))) void*)(p))
#define LPTR(p) ((__attribute__((address_space(3))) void*)(p))

__device__ __forceinline__ u16 f2bf(float f) {
    union { float f; unsigned u; } a; a.f = f;
    unsigned r = a.u + 0x7FFFu + ((a.u >> 16) & 1u);  // RNE
    return (u16)(r >> 16);
}

// ---------------- K0: f32 -> bf16 convert ----------------
__global__ __launch_bounds__(256) void cvt_kernel(const float* __restrict__ in,
                                                  u16* __restrict__ out, int n) {
    int i = (blockIdx.x * 256 + threadIdx.x) * 4;
    if (i >= n) return;
    f32x4 v = *(const f32x4*)(in + i);
    u16x4 o;
#pragma unroll
    for (int j = 0; j < 4; ++j) o[j] = f2bf(v[j]);
    *(u16x4*)(out + i) = o;
}

// ---------------- K3: Wb[b] = bf16(proj_w * mask_proj[y[b]]) ----------------
__global__ __launch_bounds__(256) void build_w_kernel(const float* __restrict__ proj_w,
                                                      const float* __restrict__ mask_proj,
                                                      const int* __restrict__ y,
                                                      u16* __restrict__ Wb) {
    int b = blockIdx.y;
    size_t mbase = (size_t)y[b] * 589824;
    int i = (blockIdx.x * 256 + threadIdx.x) * 4;
    f32x4 m = *(const f32x4*)(mask_proj + mbase + i);
    f32x4 p = *(const f32x4*)(proj_w + i);
    u16x4 o;
#pragma unroll
    for (int j = 0; j < 4; ++j) o[j] = f2bf(m[j] * p[j]);
    *(u16x4*)(Wb + (size_t)b * 589824 + i) = o;
}

// ---------------- K1: QKV GEMM 6304x2304x768 (A, B^T both K-major) ----------------
// 128x128 tile, BK=32, 4 waves (2x2), each wave 64x64 = 4x4 mfma_16x16x32 frags.
__global__ __launch_bounds__(256) void qkv_gemm_kernel(
    const u16* __restrict__ A,       // [6400][768] bf16 x
    const u16* __restrict__ Bm,      // [2304][768] bf16 qkv_w
    const float* __restrict__ bias,  // [2304]
    u16* __restrict__ qb, u16* __restrict__ kb, u16* __restrict__ vb) {
    __shared__ __align__(16) u16 As[128 * 32];
    __shared__ __align__(16) u16 Bs[128 * 32];
    const int tid = threadIdx.x;
    const int w = tid >> 6, l = tid & 63;
    const int wy = w >> 1, wx = w & 1;
    const int bm = blockIdx.y, bn = blockIdx.x;

    f32x4 acc[4][4] = {};

    const int srow = l >> 2;       // 0..15
    const int scol = (l & 3) * 8;  // 0,8,16,24
    const size_t abase = (size_t)(bm * 128 + srow) * 768 + scol;
    const size_t bbase = (size_t)(bn * 128 + srow) * 768 + scol;

    for (int kt = 0; kt < 768; kt += 32) {
#pragma unroll
        for (int cc = 0; cc < 2; ++cc) {
            int c = cc * 4 + w;  // chunk: 16 rows = 1024 B
            __builtin_amdgcn_global_load_lds(GPTR(A + abase + (size_t)c * 16 * 768 + kt),
                                             LPTR(As + c * 512 + l * 8), 16, 0, 0);
            __builtin_amdgcn_global_load_lds(GPTR(Bm + bbase + (size_t)c * 16 * 768 + kt),
                                             LPTR(Bs + c * 512 + l * 8), 16, 0, 0);
        }
        __syncthreads();
        short8 af[4], bf[4];
#pragma unroll
        for (int mi = 0; mi < 4; ++mi)
            af[mi] = *(const short8*)&As[(wy * 64 + mi * 16 + (l & 15)) * 32 + (l >> 4) * 8];
#pragma unroll
        for (int ni = 0; ni < 4; ++ni)
            bf[ni] = *(const short8*)&Bs[(wx * 64 + ni * 16 + (l & 15)) * 32 + (l >> 4) * 8];
#pragma unroll
        for (int mi = 0; mi < 4; ++mi)
#pragma unroll
            for (int ni = 0; ni < 4; ++ni)
                acc[mi][ni] = __builtin_amdgcn_mfma_f32_16x16x32_bf16(af[mi], bf[ni], acc[mi][ni], 0, 0, 0);
        __syncthreads();
    }

    // epilogue: split into q/k/v (B,H,N,D) bf16; SCALE folded into q
#pragma unroll
    for (int ni = 0; ni < 4; ++ni) {
        int col = bn * 128 + wx * 64 + ni * 16 + (l & 15);
        int s = (col >= 1536) ? 2 : (col >= 768) ? 1 : 0;
        int j = col - s * 768;
        int h = j >> 6, d = j & 63;
        float bv = bias[col];
        u16* dst = (s == 0) ? qb : (s == 1) ? kb : vb;
        float sc = (s == 0) ? 0.125f : 1.0f;
#pragma unroll
        for (int mi = 0; mi < 4; ++mi) {
#pragma unroll
            for (int r = 0; r < 4; ++r) {
                int row = bm * 128 + wy * 64 + mi * 16 + (l >> 4) * 4 + r;
                if (row < 6304) {
                    int bi = row / 197;
                    int n = row - bi * 197;
                    dst[((size_t)(bi * 12 + h) * 197 + n) * 64 + d] = f2bf((acc[mi][ni][r] + bv) * sc);
                }
            }
        }
    }
}

// ---------------- K2: attention per (b,h) ----------------
// K [208][64] zero-padded, V^T [64][224] zero-padded, P per-wave [16][224].
__global__ __launch_bounds__(256) void attn_kernel(
    const u16* __restrict__ qg_all, const u16* __restrict__ kg_all, const u16* __restrict__ vg_all,
    const int* __restrict__ y, const float* __restrict__ mask_attn,
    u16* __restrict__ omid) {
    __shared__ __align__(16) u16 Ks[208 * 64];
    __shared__ __align__(16) u16 Vst[64 * 224];
    __shared__ __align__(16) u16 Ps[4][16 * 224];
    const int bh = blockIdx.x;
    const int b = bh / 12, h = bh % 12;
    const int tid = threadIdx.x, w = tid >> 6, l = tid & 63;
    const size_t base = (size_t)bh * 197 * 64;
    const u16* qg = qg_all + base;
    const u16* kg = kg_all + base;
    const u16* vg = vg_all + base;
    const short8 zero8 = {0, 0, 0, 0, 0, 0, 0, 0};

    for (int c = tid; c < 208 * 8; c += 256) {  // K tile, zero pad rows 197..207
        int row = c >> 3, col = (c & 7) << 3;
        short8 val = zero8;
        if (row < 197) val = *(const short8*)(kg + row * 64 + col);
        *(short8*)&Ks[row * 64 + col] = val;
    }
    for (int c = tid; c < 224 * 8; c += 256) {  // V transposed, zero pad keys 197..223
        int row = c >> 3, col = (c & 7) << 3;
        short8 val = zero8;
        if (row < 197) val = *(const short8*)(vg + row * 64 + col);
#pragma unroll
        for (int j = 0; j < 8; ++j) Vst[(col + j) * 224 + row] = (u16)val[j];
    }
    __syncthreads();

    const int ycls = y[b];

    for (int ci = w; ci < 13; ci += 4) {  // 16-row query chunks round-robin over waves
        int qrow = ci * 16 + (l & 15);
        const u16* qr = qg + (size_t)qrow * 64 + ((l >> 4) * 8);
        short8 a0 = *(const short8*)(qr);
        short8 a1 = *(const short8*)(qr + 32);

        f32x4 sc[13];
#pragma unroll
        for (int jb = 0; jb < 13; ++jb) {
            short8 b0 = *(const short8*)&Ks[(jb * 16 + (l & 15)) * 64 + ((l >> 4) * 8)];
            short8 b1 = *(const short8*)&Ks[(jb * 16 + (l & 15)) * 64 + 32 + ((l >> 4) * 8)];
            f32x4 t = {0.f, 0.f, 0.f, 0.f};
            t = __builtin_amdgcn_mfma_f32_16x16x32_bf16(a0, b0, t, 0, 0, 0);
            t = __builtin_amdgcn_mfma_f32_16x16x32_bf16(a1, b1, t, 0, 0, 0);
            sc[jb] = t;
        }

        // wave-parallel softmax: rows live in 16-lane groups
#pragma unroll
        for (int r = 0; r < 4; ++r) {
            float m = -1e30f;
#pragma unroll
            for (int jb = 0; jb < 13; ++jb) {
                int colk = jb * 16 + (l & 15);
                float xv = (colk < 197) ? sc[jb][r] : -1e30f;
                sc[jb][r] = xv;
                m = fmaxf(m, xv);
            }
            m = fmaxf(m, __shfl_xor(m, 1));
            m = fmaxf(m, __shfl_xor(m, 2));
            m = fmaxf(m, __shfl_xor(m, 4));
            m = fmaxf(m, __shfl_xor(m, 8));
            float ssum = 0.f;
#pragma unroll
            for (int jb = 0; jb < 13; ++jb) {
                float e = __expf(sc[jb][r] - m);
                sc[jb][r] = e;
                ssum += e;
            }
            ssum += __shfl_xor(ssum, 1);
            ssum += __shfl_xor(ssum, 2);
            ssum += __shfl_xor(ssum, 4);
            ssum += __shfl_xor(ssum, 8);
            float inv = 1.0f / ssum;
            int prow = (l >> 4) * 4 + r;
#pragma unroll
            for (int jb = 0; jb < 13; ++jb)
                Ps[w][prow * 224 + jb * 16 + (l & 15)] = f2bf(sc[jb][r] * inv);
            Ps[w][prow * 224 + 208 + (l & 15)] = 0;  // zero pad cols 208..223
        }

        // PV: O(16x64) = P(16x224) @ V(224x64), K-steps of 32
#pragma unroll
        for (int db = 0; db < 4; ++db) {
            f32x4 o = {0.f, 0.f, 0.f, 0.f};
#pragma unroll
            for (int kt = 0; kt < 7; ++kt) {
                short8 pa = *(const short8*)&Ps[w][(l & 15) * 224 + kt * 32 + (l >> 4) * 8];
                short8 vb8 = *(const short8*)&Vst[(db * 16 + (l & 15)) * 224 + kt * 32 + (l >> 4) * 8];
                o = __builtin_amdgcn_mfma_f32_16x16x32_bf16(pa, vb8, o, 0, 0, 0);
            }
            int d = db * 16 + (l & 15);
            float mv = mask_attn[((size_t)ycls * 12 + h) * 64 + d];
#pragma unroll
            for (int r = 0; r < 4; ++r) {
                int row = ci * 16 + (l >> 4) * 4 + r;
                if (row < 197)
                    omid[((size_t)b * 197 + row) * 768 + h * 64 + d] = f2bf(o[r] * mv);
            }
        }
    }
}

// ---------------- K4: per-sample proj GEMM 197x768x768 ----------------
__global__ __launch_bounds__(256) void proj_gemm_kernel(
    const u16* __restrict__ A,       // omid [6400][768] bf16
    const u16* __restrict__ Wb,      // [32][768][768] bf16
    const float* __restrict__ bias,  // [768]
    float* __restrict__ out) {       // [32][197][768] f32
    __shared__ __align__(16) u16 As[128 * 32];
    __shared__ __align__(16) u16 Bs[128 * 32];
    const int tid = threadIdx.x;
    const int w = tid >> 6, l = tid & 63;
    const int wy = w >> 1, wx = w & 1;
    const int b = blockIdx.y;
    const int mb = blockIdx.x / 6, bn = blockIdx.x % 6;

    f32x4 acc[4][4] = {};

    const int srow = l >> 2, scol = (l & 3) * 8;
    const size_t abase = (size_t)(b * 197 + mb * 128 + srow) * 768 + scol;
    const size_t bbase = (size_t)b * 589824 + (size_t)(bn * 128 + srow) * 768 + scol;

    for (int kt = 0; kt < 768; kt += 32) {
#pragma unroll
        for (int cc = 0; cc < 2; ++cc) {
            int c = cc * 4 + w;
            __builtin_amdgcn_global_load_lds(GPTR(A + abase + (size_t)c * 16 * 768 + kt),
                                             LPTR(As + c * 512 + l * 8), 16, 0, 0);
            __builtin_amdgcn_global_load_lds(GPTR(Wb + bbase + (size_t)c * 16 * 768 + kt),
                                             LPTR(Bs + c * 512 + l * 8), 16, 0, 0);
        }
        __syncthreads();
        short8 af[4], bf[4];
#pragma unroll
        for (int mi = 0; mi < 4; ++mi)
            af[mi] = *(const short8*)&As[(wy * 64 + mi * 16 + (l & 15)) * 32 + (l >> 4) * 8];
#pragma unroll
        for (int ni = 0; ni < 4; ++ni)
            bf[ni] = *(const short8*)&Bs[(wx * 64 + ni * 16 + (l & 15)) * 32 + (l >> 4) * 8];
#pragma unroll
        for (int mi = 0; mi < 4; ++mi)
#pragma unroll
            for (int ni = 0; ni < 4; ++ni)
                acc[mi][ni] = __builtin_amdgcn_mfma_f32_16x16x32_bf16(af[mi], bf[ni], acc[mi][ni], 0, 0, 0);
        __syncthreads();
    }

#pragma unroll
    for (int ni = 0; ni < 4; ++ni) {
        int col = bn * 128 + wx * 64 + ni * 16 + (l & 15);
        float bv = bias[col];
#pragma unroll
        for (int mi = 0; mi < 4; ++mi) {
#pragma unroll
            for (int r = 0; r < 4; ++r) {
                int row = mb * 128 + wy * 64 + mi * 16 + (l >> 4) * 4 + r;
                if (row < 197)
                    out[((size_t)b * 197 + row) * 768 + col] = acc[mi][ni][r] + bv;
            }
        }
    }
}

extern "C" void kernel_launch(void* const* d_in, const int* in_sizes, int n_in,
                              void* d_out, int out_size, void* d_ws, size_t ws_size,
                              hipStream_t stream) {
    const float* x = (const float*)d_in[0];
    const int* y = (const int*)d_in[1];
    const float* qkv_w = (const float*)d_in[2];
    const float* qkv_b = (const float*)d_in[3];
    const float* proj_w = (const float*)d_in[4];
    const float* proj_b = (const float*)d_in[5];
    const float* mask_attn = (const float*)d_in[6];
    const float* mask_proj = (const float*)d_in[7];
    float* out = (float*)d_out;

    // workspace layout (bf16 = u16), ~90.3 MB total
    u16* xb = (u16*)d_ws;                       // [6400][768]  (pad rows 6304.. garbage-ok)
    u16* wqkvb = xb + (size_t)6400 * 768;       // [2304][768]
    u16* qb = wqkvb + (size_t)2304 * 768;       // [76288][64]  (384*197=75264 + pad)
    u16* kb = qb + (size_t)76288 * 64;
    u16* vb = kb + (size_t)76288 * 64;
    u16* omid = vb + (size_t)76288 * 64;        // [6400][768]
    u16* Wb = omid + (size_t)6400 * 768;        // [32][768][768]

    cvt_kernel<<<4728, 256, 0, stream>>>(x, xb, 4841472);
    cvt_kernel<<<1728, 256, 0, stream>>>(qkv_w, wqkvb, 1769472);
    qkv_gemm_kernel<<<dim3(18, 50), 256, 0, stream>>>(xb, wqkvb, qkv_b, qb, kb, vb);
    attn_kernel<<<384, 256, 0, stream>>>(qb, kb, vb, y, mask_attn, omid);
    build_w_kernel<<<dim3(576, 32), 256, 0, stream>>>(proj_w, mask_proj, y, Wb);
    proj_gemm_kernel<<<dim3(12, 32), 256, 0, stream>>>(omid, Wb, proj_b, out);
}

// Round 6
// 150.777 us; speedup vs baseline: 1.0913x; 1.0913x over previous
//
#include <hip/hip_runtime.h>

typedef unsigned short u16;
typedef __attribute__((ext_vector_type(8))) short short8;
typedef __attribute__((ext_vector_type(4))) short s16x4;
typedef __attribute__((ext_vector_type(4))) float f32x4;
typedef __attribute__((ext_vector_type(4))) u16 u16x4;

#define GPTR(p) ((const __attribute__((address_space(1))) void*)(p))
#define LPTR(p) ((__attribute__((address_space(3))) void*)(p))

// 16x16x16 bf16 MFMA: device pass finds the builtin; host pass parses device
// code too, so the fallback stub must be __host__ __device__.
#if __has_builtin(__builtin_amdgcn_mfma_f32_16x16x16bf16_1k)
#define MFMA16x16(a, b, c) __builtin_amdgcn_mfma_f32_16x16x16bf16_1k(a, b, c, 0, 0, 0)
#elif __has_builtin(__builtin_amdgcn_mfma_f32_16x16x16_bf16)
#define MFMA16x16(a, b, c) __builtin_amdgcn_mfma_f32_16x16x16_bf16(a, b, c, 0, 0, 0)
#else
__host__ __device__ static inline f32x4 MFMA16x16_host_stub(s16x4, s16x4, f32x4 c) { return c; }
#define MFMA16x16(a, b, c) MFMA16x16_host_stub(a, b, c)
#endif

__device__ __forceinline__ u16 f2bf(float f) {
    union { float f; unsigned u; } a; a.f = f;
    unsigned r = a.u + 0x7FFFu + ((a.u >> 16) & 1u);  // RNE
    return (u16)(r >> 16);
}

// ---------------- K0: f32 -> bf16 convert ----------------
__global__ __launch_bounds__(256) void cvt_kernel(const float* __restrict__ in,
                                                  u16* __restrict__ out, int n) {
    int i = (blockIdx.x * 256 + threadIdx.x) * 4;
    if (i >= n) return;
    f32x4 v = *(const f32x4*)(in + i);
    u16x4 o;
#pragma unroll
    for (int j = 0; j < 4; ++j) o[j] = f2bf(v[j]);
    *(u16x4*)(out + i) = o;
}

// ---------------- K1: QKV GEMM 6304x2304x768 (A, B^T both K-major) ----------------
__global__ __launch_bounds__(256) void qkv_gemm_kernel(
    const u16* __restrict__ A,       // [6400][768] bf16 x
    const u16* __restrict__ Bm,      // [2304][768] bf16 qkv_w
    const float* __restrict__ bias,  // [2304]
    u16* __restrict__ qb, u16* __restrict__ kb, u16* __restrict__ vb) {
    __shared__ __align__(16) u16 As[128 * 32];
    __shared__ __align__(16) u16 Bs[128 * 32];
    const int tid = threadIdx.x;
    const int w = tid >> 6, l = tid & 63;
    const int wy = w >> 1, wx = w & 1;
    const int bm = blockIdx.y, bn = blockIdx.x;

    f32x4 acc[4][4] = {};

    const int srow = l >> 2;       // 0..15
    const int scol = (l & 3) * 8;  // 0,8,16,24
    const size_t abase = (size_t)(bm * 128 + srow) * 768 + scol;
    const size_t bbase = (size_t)(bn * 128 + srow) * 768 + scol;

    for (int kt = 0; kt < 768; kt += 32) {
#pragma unroll
        for (int cc = 0; cc < 2; ++cc) {
            int c = cc * 4 + w;  // chunk: 16 rows = 1024 B
            __builtin_amdgcn_global_load_lds(GPTR(A + abase + (size_t)c * 16 * 768 + kt),
                                             LPTR(As + c * 512 + l * 8), 16, 0, 0);
            __builtin_amdgcn_global_load_lds(GPTR(Bm + bbase + (size_t)c * 16 * 768 + kt),
                                             LPTR(Bs + c * 512 + l * 8), 16, 0, 0);
        }
        __syncthreads();
        short8 af[4], bf[4];
#pragma unroll
        for (int mi = 0; mi < 4; ++mi)
            af[mi] = *(const short8*)&As[(wy * 64 + mi * 16 + (l & 15)) * 32 + (l >> 4) * 8];
#pragma unroll
        for (int ni = 0; ni < 4; ++ni)
            bf[ni] = *(const short8*)&Bs[(wx * 64 + ni * 16 + (l & 15)) * 32 + (l >> 4) * 8];
#pragma unroll
        for (int mi = 0; mi < 4; ++mi)
#pragma unroll
            for (int ni = 0; ni < 4; ++ni)
                acc[mi][ni] = __builtin_amdgcn_mfma_f32_16x16x32_bf16(af[mi], bf[ni], acc[mi][ni], 0, 0, 0);
        __syncthreads();
    }

    // epilogue: split into q/k/v (B,H,N,D) bf16; SCALE folded into q
#pragma unroll
    for (int ni = 0; ni < 4; ++ni) {
        int col = bn * 128 + wx * 64 + ni * 16 + (l & 15);
        int s = (col >= 1536) ? 2 : (col >= 768) ? 1 : 0;
        int j = col - s * 768;
        int h = j >> 6, d = j & 63;
        float bv = bias[col];
        u16* dst = (s == 0) ? qb : (s == 1) ? kb : vb;
        float sc = (s == 0) ? 0.125f : 1.0f;
#pragma unroll
        for (int mi = 0; mi < 4; ++mi) {
#pragma unroll
            for (int r = 0; r < 4; ++r) {
                int row = bm * 128 + wy * 64 + mi * 16 + (l >> 4) * 4 + r;
                if (row < 6304) {
                    int bi = row / 197;
                    int n = row - bi * 197;
                    dst[((size_t)(bi * 12 + h) * 197 + n) * 64 + d] = f2bf((acc[mi][ni][r] + bv) * sc);
                }
            }
        }
    }
}

// ---------------- K2: attention per (b,h), swapped-QK^T in-register softmax ----------------
// S^T = mfma(A=K, B=Q): lane (q=l&15, g=l>>4) holds S^T[kk=16jb+4g+r][q].
// P fragment feeds 16x16x16 PV directly (k=(l>>4)*4+j == 4g+r). No P LDS.
#define VPAD 228
__global__ __launch_bounds__(256) void attn_kernel(
    const u16* __restrict__ qg_all, const u16* __restrict__ kg_all, const u16* __restrict__ vg_all,
    const int* __restrict__ y, const float* __restrict__ mask_attn,
    u16* __restrict__ omid) {
    __shared__ __align__(16) u16 Ks[208 * 64];    // XOR-swizzled rows
    __shared__ __align__(16) u16 Vst[64 * VPAD];  // V^T, padded rows
    const int bh = blockIdx.x;
    const int b = bh / 12, h = bh % 12;
    const int tid = threadIdx.x, w = tid >> 6, l = tid & 63;
    const int dl = l & 15, g = l >> 4;
    const size_t base = (size_t)bh * 197 * 64;
    const u16* qg = qg_all + base;
    const u16* kg = kg_all + base;
    const u16* vg = vg_all + base;
    const short8 zero8 = {0, 0, 0, 0, 0, 0, 0, 0};

    for (int c = tid; c < 208 * 8; c += 256) {  // K tile, swizzled, zero pad rows 197..207
        int row = c >> 3, colb = (c & 7) * 16;
        short8 val = zero8;
        if (row < 197) val = *(const short8*)(kg + row * 64 + (c & 7) * 8);
        int bo = (row * 128 + colb) ^ ((row & 7) << 4);
        *(short8*)((char*)Ks + bo) = val;
    }
    for (int c = tid; c < 208 * 8; c += 256) {  // V transposed, zero pad keys 197..207
        int row = c >> 3, col = (c & 7) * 8;
        short8 val = zero8;
        if (row < 197) val = *(const short8*)(vg + row * 64 + col);
#pragma unroll
        for (int j = 0; j < 8; ++j) Vst[(col + j) * VPAD + row] = (u16)val[j];
    }
    __syncthreads();

    const int ycls = y[b];

    for (int ci = w; ci < 13; ci += 4) {
        int qrow = ci * 16 + dl;
        const u16* qr = qg + (size_t)qrow * 64 + g * 8;
        short8 q0 = *(const short8*)(qr);
        short8 q1 = *(const short8*)(qr + 32);

        f32x4 sc[13];
#pragma unroll
        for (int jb = 0; jb < 13; ++jb) {
            int krow = jb * 16 + dl;
            int sw = (krow & 7) << 4;
            short8 k0 = *(const short8*)((const char*)Ks + ((krow * 128 + g * 16) ^ sw));
            short8 k1 = *(const short8*)((const char*)Ks + ((krow * 128 + 64 + g * 16) ^ sw));
            f32x4 t = {0.f, 0.f, 0.f, 0.f};
            t = __builtin_amdgcn_mfma_f32_16x16x32_bf16(k0, q0, t, 0, 0, 0);
            t = __builtin_amdgcn_mfma_f32_16x16x32_bf16(k1, q1, t, 0, 0, 0);
            sc[jb] = t;
        }
        // mask invalid keys (only jb=12: kk=192+4g+r >= 197)
#pragma unroll
        for (int r = 0; r < 4; ++r)
            if (192 + g * 4 + r >= 197) sc[12][r] = -1e30f;

        // softmax over kk: 52 in-lane + shfl over lane+16/32
        float mx = -1e30f;
#pragma unroll
        for (int jb = 0; jb < 13; ++jb)
#pragma unroll
            for (int r = 0; r < 4; ++r) mx = fmaxf(mx, sc[jb][r]);
        mx = fmaxf(mx, __shfl_xor(mx, 16));
        mx = fmaxf(mx, __shfl_xor(mx, 32));
        float ssum = 0.f;
#pragma unroll
        for (int jb = 0; jb < 13; ++jb)
#pragma unroll
            for (int r = 0; r < 4; ++r) {
                float e = __expf(sc[jb][r] - mx);
                sc[jb][r] = e;
                ssum += e;
            }
        ssum += __shfl_xor(ssum, 16);
        ssum += __shfl_xor(ssum, 32);
        float inv = 1.0f / ssum;

        s16x4 pb[13];
#pragma unroll
        for (int jb = 0; jb < 13; ++jb) {
            s16x4 pv;
#pragma unroll
            for (int r = 0; r < 4; ++r) pv[r] = (short)f2bf(sc[jb][r] * inv);
            pb[jb] = pv;
        }

        // PV: o^T[d][q] = sum_kk V^T[d][kk] * P^T[kk][q], 16x16x16 K-steps.
        // MFMA is cross-lane (A-fragments of ALL 64 lanes feed every output
        // column), so the whole wave executes it uniformly; only the store is
        // per-lane predicated. (A divergent-branch MFMA here fed stale regs
        // from masked-off lanes -> NaN. R5 lesson.)
#pragma unroll
        for (int db = 0; db < 4; ++db) {
            f32x4 o = {0.f, 0.f, 0.f, 0.f};
#pragma unroll
            for (int jb = 0; jb < 13; ++jb) {
                s16x4 va = *(const s16x4*)&Vst[(db * 16 + dl) * VPAD + jb * 16 + g * 4];
                o = MFMA16x16(va, pb[jb], o);
            }
            if (qrow < 197) {
                int d = db * 16 + g * 4;
                f32x4 mv = *(const f32x4*)(mask_attn + ((size_t)ycls * 12 + h) * 64 + d);
                u16x4 ov;
#pragma unroll
                for (int r = 0; r < 4; ++r) ov[r] = f2bf(o[r] * mv[r]);
                *(u16x4*)(omid + ((size_t)b * 197 + qrow) * 768 + h * 64 + d) = ov;
            }
        }
    }
}

// ---------------- K4: per-sample proj GEMM 197x768x768, mask fused into B staging ----------------
__global__ __launch_bounds__(256) void proj_gemm_kernel(
    const u16* __restrict__ A,          // omid [6400][768] bf16
    const float* __restrict__ proj_w,   // [768][768] f32
    const float* __restrict__ mask_proj,// [100][768][768] f32
    const int* __restrict__ y,
    const float* __restrict__ bias,     // [768]
    float* __restrict__ out) {          // [32][197][768] f32
    __shared__ __align__(16) u16 As[128 * 32];
    __shared__ __align__(16) u16 Bs[128 * 32];
    const int tid = threadIdx.x;
    const int w = tid >> 6, l = tid & 63;
    const int wy = w >> 1, wx = w & 1;
    const int b = blockIdx.y;
    const int mb = blockIdx.x / 6, bn = blockIdx.x % 6;
    const size_t mbase = (size_t)y[b] * 589824;

    f32x4 acc[4][4] = {};

    const int srow = l >> 2, scol = (l & 3) * 8;
    const size_t abase = (size_t)(b * 197 + mb * 128 + srow) * 768 + scol;

    for (int kt = 0; kt < 768; kt += 32) {
#pragma unroll
        for (int cc = 0; cc < 2; ++cc) {
            int c = cc * 4 + w;
            __builtin_amdgcn_global_load_lds(GPTR(A + abase + (size_t)c * 16 * 768 + kt),
                                             LPTR(As + c * 512 + l * 8), 16, 0, 0);
        }
#pragma unroll
        for (int cc = 0; cc < 2; ++cc) {  // fused B staging: bf16(proj_w * mask_proj[y])
            int c = cc * 4 + w;
            int grow = bn * 128 + c * 16 + srow;
            size_t goff = (size_t)grow * 768 + kt + scol;
            f32x4 p0 = *(const f32x4*)(proj_w + goff);
            f32x4 p1 = *(const f32x4*)(proj_w + goff + 4);
            f32x4 m0 = *(const f32x4*)(mask_proj + mbase + goff);
            f32x4 m1 = *(const f32x4*)(mask_proj + mbase + goff + 4);
            short8 ov;
#pragma unroll
            for (int j = 0; j < 4; ++j) {
                ov[j] = (short)f2bf(p0[j] * m0[j]);
                ov[4 + j] = (short)f2bf(p1[j] * m1[j]);
            }
            *(short8*)&Bs[(c * 16 + srow) * 32 + scol] = ov;
        }
        __syncthreads();
        short8 af[4], bf[4];
#pragma unroll
        for (int mi = 0; mi < 4; ++mi)
            af[mi] = *(const short8*)&As[(wy * 64 + mi * 16 + (l & 15)) * 32 + (l >> 4) * 8];
#pragma unroll
        for (int ni = 0; ni < 4; ++ni)
            bf[ni] = *(const short8*)&Bs[(wx * 64 + ni * 16 + (l & 15)) * 32 + (l >> 4) * 8];
#pragma unroll
        for (int mi = 0; mi < 4; ++mi)
#pragma unroll
            for (int ni = 0; ni < 4; ++ni)
                acc[mi][ni] = __builtin_amdgcn_mfma_f32_16x16x32_bf16(af[mi], bf[ni], acc[mi][ni], 0, 0, 0);
        __syncthreads();
    }

#pragma unroll
    for (int ni = 0; ni < 4; ++ni) {
        int col = bn * 128 + wx * 64 + ni * 16 + (l & 15);
        float bv = bias[col];
#pragma unroll
        for (int mi = 0; mi < 4; ++mi) {
#pragma unroll
            for (int r = 0; r < 4; ++r) {
                int row = mb * 128 + wy * 64 + mi * 16 + (l >> 4) * 4 + r;
                if (row < 197)
                    out[((size_t)b * 197 + row) * 768 + col] = acc[mi][ni][r] + bv;
            }
        }
    }
}

extern "C" void kernel_launch(void* const* d_in, const int* in_sizes, int n_in,
                              void* d_out, int out_size, void* d_ws, size_t ws_size,
                              hipStream_t stream) {
    const float* x = (const float*)d_in[0];
    const int* y = (const int*)d_in[1];
    const float* qkv_w = (const float*)d_in[2];
    const float* qkv_b = (const float*)d_in[3];
    const float* proj_w = (const float*)d_in[4];
    const float* proj_b = (const float*)d_in[5];
    const float* mask_attn = (const float*)d_in[6];
    const float* mask_proj = (const float*)d_in[7];
    float* out = (float*)d_out;

    // workspace layout (bf16 = u16), ~52.5 MB
    u16* xb = (u16*)d_ws;                       // [6400][768]
    u16* wqkvb = xb + (size_t)6400 * 768;       // [2304][768]
    u16* qb = wqkvb + (size_t)2304 * 768;       // [76288][64]
    u16* kb = qb + (size_t)76288 * 64;
    u16* vb = kb + (size_t)76288 * 64;
    u16* omid = vb + (size_t)76288 * 64;        // [6400][768]

    cvt_kernel<<<4728, 256, 0, stream>>>(x, xb, 4841472);
    cvt_kernel<<<1728, 256, 0, stream>>>(qkv_w, wqkvb, 1769472);
    qkv_gemm_kernel<<<dim3(18, 50), 256, 0, stream>>>(xb, wqkvb, qkv_b, qb, kb, vb);
    attn_kernel<<<384, 256, 0, stream>>>(qb, kb, vb, y, mask_attn, omid);
    proj_gemm_kernel<<<dim3(12, 32), 256, 0, stream>>>(omid, proj_w, mask_proj, y, proj_b, out);
}